// Round 19
// baseline (4357.536 us; speedup 1.0000x reference)
//
#include <hip/hip_runtime.h>
#include <math.h>

// 3-layer LSTM (B=64,H=512,T=512,F=513) + FC(512)->ReLU->FC(513).
// R18 = R17 with the macro-expansion compile fix (PIPE indirection so XB/YB/ZB
//  expand before ISSUE_T/MFMA_T argument matching). Logic identical to R17:
//  R16 + COUNTED-VMCNT LOAD PIPELINING (3 rotating register buffers; issue
//  tiles 0,1 upfront; per tile: vmcnt(8) + sched_barrier + issue i+2 + MFMA i).

#define BB 64
#define HH 512
#define TT 512
#define FF 513
#define KX 544                 // padded x-K (17 tiles of 32)
#define KT1 33                 // L1 k-tiles (17 x + 16 h)
#define KT23 32
#define SBH 32768              // shorts per h slot (64*512)
#define XFT 34816              // shorts per x timestep (17*4*512)
#define XCH2 (64 * XFT)        // shorts per x ring slot: 2,228,224
#define OFF2 2162688
#define OFF3 4259840
#define TOTB 6356992
#define GRID 192
#define SPIN_CAP 5000000       // watchdog; never hit on happy path

typedef __attribute__((ext_vector_type(8))) short s16x8;
typedef __attribute__((ext_vector_type(4))) short s16x4;
typedef __attribute__((ext_vector_type(4))) float f32x4;

#define MFB(a, b, c) __builtin_amdgcn_mfma_f32_16x16x32_bf16(a, b, c, 0, 0, 0)

__device__ __forceinline__ float sigf(float x) { return 1.0f / (1.0f + expf(-x)); }

__device__ __forceinline__ float bf2f(short s) {
    return __uint_as_float(((unsigned)(unsigned short)s) << 16);
}
__device__ __forceinline__ short f2bf(float w) {   // RNE
    unsigned u = __float_as_uint(w);
    return (short)((u + 0x7fff + ((u >> 16) & 1)) >> 16);
}
__device__ __forceinline__ void bfsplit(float w, short& hi, short& lo) {
    hi = f2bf(w);
    lo = f2bf(w - bf2f(hi));
}

// ---- MALL write-through 8B stores (agent-scope relaxed atomics) ----
__device__ __forceinline__ void astore8(short* p, s16x4 v) {
    union { unsigned long long u; s16x4 s; } c; c.s = v;
    __hip_atomic_store((unsigned long long*)p, c.u,
                       __ATOMIC_RELAXED, __HIP_MEMORY_SCOPE_AGENT);
}
__device__ __forceinline__ s16x4 lo4(s16x8 v) {
    s16x4 r; r[0]=v[0]; r[1]=v[1]; r[2]=v[2]; r[3]=v[3]; return r;
}
__device__ __forceinline__ s16x4 hi4(s16x8 v) {
    s16x4 r; r[0]=v[4]; r[1]=v[5]; r[2]=v[6]; r[3]=v[7]; return r;
}

// Lane-contiguous fragment-blob address for element (b, k):
__device__ __forceinline__ int hfrag_addr(int b, int k) {
    int it = k >> 5, o32 = k & 31;
    int half = o32 >> 4, w = o32 & 15;
    int g = w >> 2, i = w & 3;
    int bt = b >> 4, rl = b & 15;
    return ((it * 4 + bt) * 64 + g * 16 + rl) * 8 + half * 4 + i;
}

// ---------- prep: initial h -> lane-contiguous fragment blobs, slot 0 ----------
__global__ __launch_bounds__(256) void prep_state_h(
    const float* __restrict__ h1, const float* __restrict__ h2,
    const float* __restrict__ h3, short* __restrict__ Hh, short* __restrict__ Hl)
{
    int idx = blockIdx.x * 256 + threadIdx.x;          // 3*32768
    int l = idx >> 15, e = idx & 32767;
    int b = e >> 9, u = e & 511;
    const float* s = l == 0 ? h1 : l == 1 ? h2 : h3;
    short hi, lo; bfsplit(s[e], hi, lo);
    int fa = hfrag_addr(b, u);
    Hh[(size_t)(l * 4) * SBH + fa] = hi;               // 4-slot ring, slot 0
    Hl[(size_t)(l * 4) * SBH + fa] = lo;
}

// ---------- prep: initial c transpose [b][u] -> cT[l][u][b] ----------
__global__ __launch_bounds__(256) void prep_state_c(
    const float* __restrict__ c1, const float* __restrict__ c2,
    const float* __restrict__ c3, float* __restrict__ cT)
{
    __shared__ float tile[64][65];
    int l = blockIdx.x >> 3, ut = blockIdx.x & 7;
    const float* s = l == 0 ? c1 : l == 1 ? c2 : c3;
    int u0 = ut * 64, tid = threadIdx.x;
#pragma unroll
    for (int p = 0; p < 16; ++p) {
        int b = p * 4 + (tid >> 6), u = tid & 63;
        tile[u][b] = s[(size_t)b * HH + u0 + u];
    }
    __syncthreads();
#pragma unroll
    for (int p = 0; p < 16; ++p) {
        int ul = p * 4 + (tid >> 6), b = tid & 63;
        cT[(size_t)l * (HH * BB) + (size_t)(u0 + ul) * BB + b] = tile[ul][b];
    }
}

// ---------- prep: bias sums, gate-interleaved j' = 4u+g ----------
__global__ __launch_bounds__(256) void prep_bias(
    const float* __restrict__ bi1, const float* __restrict__ bh1,
    const float* __restrict__ bi2, const float* __restrict__ bh2,
    const float* __restrict__ bi3, const float* __restrict__ bh3,
    float* __restrict__ bsum)
{
    int idx = blockIdx.x * 256 + threadIdx.x;          // 3*2048
    if (idx >= 6144) return;
    int l = idx >> 11, jq = idx & 2047;
    int u = jq >> 2, g = jq & 3;
    const float* bi = l == 0 ? bi1 : l == 1 ? bi2 : bi3;
    const float* bh = l == 0 ? bh1 : l == 1 ? bh2 : bh3;
    bsum[idx] = bi[g * HH + u] + bh[g * HH + u];
}

// ---------- prep: weight blobs (fragment-linear, split hi/lo) ----------
__global__ __launch_bounds__(256) void prep_blob(
    const float* __restrict__ Wih1, const float* __restrict__ Whh1,
    const float* __restrict__ Wih2, const float* __restrict__ Whh2,
    const float* __restrict__ Wih3, const float* __restrict__ Whh3,
    short* __restrict__ Bh, short* __restrict__ Bl)
{
    int idx = blockIdx.x * 256 + threadIdx.x;          // TOTB exact
    int l, e, KTl;
    if (idx < OFF2)      { l = 0; e = idx;        KTl = KT1;  }
    else if (idx < OFF3) { l = 1; e = idx - OFF2; KTl = KT23; }
    else                 { l = 2; e = idx - OFF3; KTl = KT23; }
    int jtkt = e >> 9, r = e & 511;
    int lane = r >> 3, i = r & 7;
    int jt = jtkt / KTl, kt = jtkt - jt * KTl;
    int n = lane & 15, g = (lane >> 4) & 3;
    int jq = jt * 16 + n;
    int u = jq >> 2, gate = jq & 3;
    int row = gate * HH + u;
    int kk = kt * 32 + ((i < 4) ? (g * 4 + i) : (16 + g * 4 + (i - 4)));
    float w;
    if (l == 0) {
        if (kk < KX) w = (kk < FF) ? Wih1[(size_t)row * FF + kk] : 0.f;
        else         w = Whh1[(size_t)row * HH + (kk - KX)];
    } else if (l == 1) {
        w = (kk < HH) ? Wih2[(size_t)row * HH + kk] : Whh2[(size_t)row * HH + kk - HH];
    } else {
        w = (kk < HH) ? Wih3[(size_t)row * HH + kk] : Whh3[(size_t)row * HH + kk - HH];
    }
    short hi, lo; bfsplit(w, hi, lo);
    Bh[idx] = hi; Bl[idx] = lo;
}

// ---------- prep: x chunk 0 -> FRAGMENT-LINEAR slot 0 ----------
__global__ __launch_bounds__(256) void prep_x(
    const float* __restrict__ x, short* __restrict__ Xh, short* __restrict__ Xl)
{
    __shared__ float tile[64][65];
    int b = blockIdx.x / 9, fblk = blockIdx.x % 9;
    int f0 = fblk * 64, tid = threadIdx.x;
#pragma unroll
    for (int p = 0; p < 16; ++p) {
        int fl = (tid >> 6) + p * 4, tt = tid & 63;
        int f = f0 + fl;
        tile[fl][tt] = (f < FF) ? x[((size_t)b * FF + f) * TT + tt] : 0.f;
    }
    __syncthreads();
    {
        int q = tid & 3, tt = tid >> 2;
        int fq = f0 + q * 16;
        if (fq < KX) {
            int it = fq >> 5, hf = (fq >> 4) & 1;
            s16x8 vh0, vl0, vh1, vl1;
#pragma unroll
            for (int m = 0; m < 8; ++m) {
                short hi, lo; bfsplit(tile[q * 16 + m][tt], hi, lo);
                vh0[m] = hi; vl0[m] = lo;
            }
#pragma unroll
            for (int m = 0; m < 8; ++m) {
                short hi, lo; bfsplit(tile[q * 16 + 8 + m][tt], hi, lo);
                vh1[m] = hi; vl1[m] = lo;
            }
            size_t tb = (size_t)tt * XFT
                      + (size_t)(it * 4 + (b >> 4)) * 512 + (size_t)(b & 15) * 8 + hf * 4;
            *(s16x4*)(Xh + tb      ) = lo4(vh0);
            *(s16x4*)(Xh + tb + 128) = hi4(vh0);
            *(s16x4*)(Xh + tb + 256) = lo4(vh1);
            *(s16x4*)(Xh + tb + 384) = hi4(vh1);
            *(s16x4*)(Xl + tb      ) = lo4(vl0);
            *(s16x4*)(Xl + tb + 128) = hi4(vl0);
            *(s16x4*)(Xl + tb + 256) = lo4(vl1);
            *(s16x4*)(Xl + tb + 384) = hi4(vl1);
        }
    }
}

// ---------- THE persistent kernel (8 waves, pipelined loads) ----------
__global__ __launch_bounds__(512, 1) void lstm_persist(
    const float* __restrict__ x,
    const short* __restrict__ Bh, const short* __restrict__ Bl,
    short* __restrict__ Xh, short* __restrict__ Xl,
    short* __restrict__ Hh, short* __restrict__ Hl,   // [3][4 slots][SBH]
    const float* __restrict__ bsum, const float* __restrict__ cTin,
    unsigned* __restrict__ arrive)   // [GRID * 32] (128B-padded slots)
{
    __shared__ float PfF[8 * 32 * 65];     // 66560 B; aliased as x-tile [64][65]
    __shared__ float cLDS[8 * 64];
    __shared__ float biasLDS[32];
    __shared__ short hstH[64 * 8];
    __shared__ short hstL[64 * 8];

    const int bid = (int)blockIdx.x;
    const int layer = bid >> 6;            // 0..2
    const int jb = bid & 63;               // 0..63 -> j' cols [jb*32, jb*32+32)
    const int tid = (int)threadIdx.x;
    const int lane = tid & 63;
    const int wv = __builtin_amdgcn_readfirstlane(tid >> 6);   // 0..7
    const int rl = lane & 15, g = lane >> 4;
    const int u0 = jb * 8;

    // per-wave K split: waves 0-3 = phase A, waves 4-7 = phase B
    int kt0, ktn;
    if (layer == 0) {
        if (wv < 4) { kt0 = (wv == 0) ? 0 : 5 + 4 * (wv - 1); ktn = (wv == 0) ? 5 : 4; }
        else        { kt0 = 17 + (wv - 4) * 4; ktn = 4; }
    } else {
        if (wv < 4) { kt0 = wv * 4; ktn = 4; }
        else        { kt0 = 16 + (wv - 4) * 4; ktn = 4; }
    }
    const int KTl = (layer == 0) ? KT1 : KT23;
    const size_t blobOff = (layer == 0) ? 0 : ((layer == 1) ? (size_t)OFF2 : (size_t)OFF3);

    // ---- weights -> registers (once): 2 jt x <=5 kt, hi+lo ----
    s16x8 WHr[2][5], WLr[2][5];
#pragma unroll
    for (int jj = 0; jj < 2; ++jj) {
        const int jtG = jb * 2 + jj;
#pragma unroll
        for (int it = 0; it < 5; ++it) {
            if (it < ktn) {
                size_t o = blobOff + ((size_t)(jtG * KTl + kt0 + it)) * 512 + lane * 8;
                WHr[jj][it] = *(const s16x8*)(Bh + o);
                WLr[jj][it] = *(const s16x8*)(Bl + o);
            }
        }
    }

    // ---- c slice + bias -> LDS (once) ----
    cLDS[tid] = cTin[(size_t)layer * (HH * BB) + (size_t)u0 * 64 + tid];
    if (tid < 32) biasLDS[tid] = bsum[layer * 2048 + jb * 32 + tid];
    __syncthreads();

    // producer-side fragment store geometry (block owns u0..u0+7)
    const int p_it = jb >> 2;
    const int p_o  = (jb & 3) * 8;
    const int p_hf = (p_o >= 16) ? 1 : 0;
    const int p_gA = (p_o & 8) ? 2 : 0;

    const int upGrp = (layer > 0) ? layer - 1 : 0;

    for (int t = 0; t < TT; ++t) {
        // ---- per-wave selective wait ----
        {
            int grp, thr;
            if (wv < 4) {
                if (layer == 0) { grp = 0;     thr = t & ~63; }   // x chunk ready
                else            { grp = upGrp; thr = t + 1;   }   // upstream h[t]
            } else {
                grp = layer; thr = t;                              // own h[t-1]
            }
            if (thr > 0) {
                int guard = 0;
                for (;;) {
                    unsigned v = __hip_atomic_load(&arrive[(grp * 64 + lane) * 32],
                                  __ATOMIC_RELAXED, __HIP_MEMORY_SCOPE_AGENT);
                    if (__all((int)v >= thr)) break;
                    if (++guard > SPIN_CAP) break;   // degrade visibly
                    __builtin_amdgcn_s_sleep(1);
                }
            }
        }

        // ---- A fragment base (x and h share one layout & load path) ----
        const short* fH; const short* fL; int itg0;
        if (layer == 0) {
            if (wv < 4) {
                size_t xb = (size_t)((t >> 6) & 1) * XCH2 + (size_t)(t & 63) * XFT;
                fH = Xh + xb; fL = Xl + xb; itg0 = kt0;
            } else {
                size_t hb = (size_t)(0 * 4 + (t & 3)) * SBH;       // own h[t-1]
                fH = Hh + hb; fL = Hl + hb; itg0 = kt0 - 17;
            }
        } else if (layer == 1) {
            size_t hb;
            if (wv < 4) { hb = (size_t)(0 * 4 + ((t + 1) & 3)) * SBH; itg0 = kt0; }      // h0[t]
            else        { hb = (size_t)(1 * 4 + (t & 3)) * SBH;       itg0 = kt0 - 16; } // h1[t-1]
            fH = Hh + hb; fL = Hl + hb;
        } else {
            size_t hb;
            if (wv < 4) { hb = (size_t)(1 * 4 + ((t + 1) & 3)) * SBH; itg0 = kt0; }      // h1[t]
            else        { hb = (size_t)(2 * 4 + (t & 3)) * SBH;       itg0 = kt0 - 16; } // h2[t-1]
            fH = Hh + hb; fL = Hl + hb;
        }

        f32x4 acc[2][4];
#pragma unroll
        for (int jj = 0; jj < 2; ++jj)
#pragma unroll
            for (int bt = 0; bt < 4; ++bt) acc[jj][bt] = (f32x4){0.f, 0.f, 0.f, 0.f};

        // ---- pipelined loads: 3 rotating buffers, counted vmcnt ----
        s16x8 bX0, bX1, bX2, bX3, bX4, bX5, bX6, bX7;
        s16x8 bY0, bY1, bY2, bY3, bY4, bY5, bY6, bY7;
        s16x8 bZ0, bZ1, bZ2, bZ3, bZ4, bZ5, bZ6, bZ7;

#define PIPE(M, ...) M(__VA_ARGS__)

#define ISSUE_T(B0,B1,B2,B3,B4,B5,B6,B7, IT)                              \
        {                                                                 \
            const int fb_ = (itg0 + (IT)) * 4;                            \
            const short* q0 = fH + (size_t)(fb_ + 0) * 512 + lane * 8;    \
            const short* q1 = fH + (size_t)(fb_ + 1) * 512 + lane * 8;    \
            const short* q2 = fH + (size_t)(fb_ + 2) * 512 + lane * 8;    \
            const short* q3 = fH + (size_t)(fb_ + 3) * 512 + lane * 8;    \
            const short* q4 = fL + (size_t)(fb_ + 0) * 512 + lane * 8;    \
            const short* q5 = fL + (size_t)(fb_ + 1) * 512 + lane * 8;    \
            const short* q6 = fL + (size_t)(fb_ + 2) * 512 + lane * 8;    \
            const short* q7 = fL + (size_t)(fb_ + 3) * 512 + lane * 8;    \
            asm volatile(                                                 \
                "global_load_dwordx4 %0, %8, off sc0 sc1\n\t"             \
                "global_load_dwordx4 %1, %9, off sc0 sc1\n\t"             \
                "global_load_dwordx4 %2, %10, off sc0 sc1\n\t"            \
                "global_load_dwordx4 %3, %11, off sc0 sc1\n\t"            \
                "global_load_dwordx4 %4, %12, off sc0 sc1\n\t"            \
                "global_load_dwordx4 %5, %13, off sc0 sc1\n\t"            \
                "global_load_dwordx4 %6, %14, off sc0 sc1\n\t"            \
                "global_load_dwordx4 %7, %15, off sc0 sc1"                \
                : "=&v"(B0), "=&v"(B1), "=&v"(B2), "=&v"(B3),             \
                  "=&v"(B4), "=&v"(B5), "=&v"(B6), "=&v"(B7)              \
                : "v"(q0), "v"(q1), "v"(q2), "v"(q3),                     \
                  "v"(q4), "v"(q5), "v"(q6), "v"(q7)                      \
                : "memory");                                              \
        }

#define WAITN(N)                                                          \
        asm volatile("s_waitcnt vmcnt(" #N ")" ::: "memory");             \
        __builtin_amdgcn_sched_barrier(0);

#define MFMA_T(B0,B1,B2,B3,B4,B5,B6,B7, IT)                               \
        _Pragma("unroll")                                                 \
        for (int jj = 0; jj < 2; ++jj) {                                  \
            acc[jj][0] = MFB(B0, WHr[jj][IT], acc[jj][0]);                \
            acc[jj][0] = MFB(B4, WHr[jj][IT], acc[jj][0]);                \
            acc[jj][0] = MFB(B0, WLr[jj][IT], acc[jj][0]);                \
            acc[jj][1] = MFB(B1, WHr[jj][IT], acc[jj][1]);                \
            acc[jj][1] = MFB(B5, WHr[jj][IT], acc[jj][1]);                \
            acc[jj][1] = MFB(B1, WLr[jj][IT], acc[jj][1]);                \
            acc[jj][2] = MFB(B2, WHr[jj][IT], acc[jj][2]);                \
            acc[jj][2] = MFB(B6, WHr[jj][IT], acc[jj][2]);                \
            acc[jj][2] = MFB(B2, WLr[jj][IT], acc[jj][2]);                \
            acc[jj][3] = MFB(B3, WHr[jj][IT], acc[jj][3]);                \
            acc[jj][3] = MFB(B7, WHr[jj][IT], acc[jj][3]);                \
            acc[jj][3] = MFB(B3, WLr[jj][IT], acc[jj][3]);                \
        }

#define XB bX0,bX1,bX2,bX3,bX4,bX5,bX6,bX7
#define YB bY0,bY1,bY2,bY3,bY4,bY5,bY6,bY7
#define ZB bZ0,bZ1,bZ2,bZ3,bZ4,bZ5,bZ6,bZ7

        if (layer == 0 && wv == 0) {          // 5 k-tiles
            PIPE(ISSUE_T, XB, 0)
            PIPE(ISSUE_T, YB, 1)
            WAITN(8) PIPE(ISSUE_T, ZB, 2) PIPE(MFMA_T, XB, 0)
            WAITN(8) PIPE(ISSUE_T, XB, 3) PIPE(MFMA_T, YB, 1)
            WAITN(8) PIPE(ISSUE_T, YB, 4) PIPE(MFMA_T, ZB, 2)
            WAITN(8) PIPE(MFMA_T, XB, 3)
            WAITN(0) PIPE(MFMA_T, YB, 4)
        } else {                              // 4 k-tiles
            PIPE(ISSUE_T, XB, 0)
            PIPE(ISSUE_T, YB, 1)
            WAITN(8) PIPE(ISSUE_T, ZB, 2) PIPE(MFMA_T, XB, 0)
            WAITN(8) PIPE(ISSUE_T, XB, 3) PIPE(MFMA_T, YB, 1)
            WAITN(8) PIPE(MFMA_T, ZB, 2)
            WAITN(0) PIPE(MFMA_T, XB, 3)
        }
#undef ISSUE_T
#undef WAITN
#undef MFMA_T
#undef XB
#undef YB
#undef ZB
#undef PIPE

        // ---- partial reduce across 8 waves ----
        __syncthreads();   // prev step's readers of PfF done
#pragma unroll
        for (int jj = 0; jj < 2; ++jj)
#pragma unroll
            for (int bt = 0; bt < 4; ++bt)
#pragma unroll
                for (int r = 0; r < 4; ++r)
                    PfF[(wv * 32 + jj * 16 + rl) * 65 + bt * 16 + g * 4 + r] = acc[jj][bt][r];
        __syncthreads();

        {   // gates + pointwise: 512 threads cover (ul 0..7) x (b 0..63)
            const int half = tid >> 8;             // 0..1
            const int r5 = tid & 255;
            const int ul = r5 >> 5, bl = r5 & 31;
            const int b = half * 32 + bl;
            float G[4];
#pragma unroll
            for (int gi = 0; gi < 4; ++gi) {
                const int jl = ul * 4 + gi;
                float v = 0.f;
#pragma unroll
                for (int w8 = 0; w8 < 8; ++w8)
                    v += PfF[(w8 * 32 + jl) * 65 + b];
                G[gi] = v + biasLDS[jl];
            }
            float cold = cLDS[ul * 64 + b];
            float cn = sigf(G[1]) * cold + sigf(G[0]) * tanhf(G[2]);
            float hn = sigf(G[3]) * tanhf(cn);
            cLDS[ul * 64 + b] = cn;
            short hi, lo; bfsplit(hn, hi, lo);
            hstH[b * 8 + ul] = hi;
            hstL[b * 8 + ul] = lo;
        }
        __syncthreads();

        if (tid < 64) {
            // WAR: downstream group must have consumed h[t-4] (arrive >= t-2)
            if (layer < 2) {
                const int thr = t - 2;
                if (thr > 0) {
                    int guard = 0;
                    for (;;) {
                        unsigned v = __hip_atomic_load(&arrive[((layer + 1) * 64 + lane) * 32],
                                      __ATOMIC_RELAXED, __HIP_MEMORY_SCOPE_AGENT);
                        if (__all((int)v >= thr)) break;
                        if (++guard > SPIN_CAP) break;
                        __builtin_amdgcn_s_sleep(1);
                    }
                }
            }
            // write h slice -> lane-contiguous blob slot (t+1)&3 (write-through)
            const int b = tid, bt = b >> 4, prl = b & 15;
            const size_t base = (size_t)(layer * 4 + ((t + 1) & 3)) * SBH
                              + (size_t)(p_it * 4 + bt) * 512 + p_hf * 4;
            const size_t aA = base + (size_t)(p_gA * 16 + prl) * 8;
            const size_t aB = base + (size_t)((p_gA + 1) * 16 + prl) * 8;
            s16x8 vh = *(const s16x8*)(hstH + b * 8);
            s16x8 vl = *(const s16x8*)(hstL + b * 8);
            astore8(Hh + aA, lo4(vh));
            astore8(Hh + aB, hi4(vh));
            astore8(Hl + aA, lo4(vl));
            astore8(Hl + aB, hi4(vl));
        }

        // ---- x-transpose of NEXT chunk at end of steps t%64==63 (layer 0) ----
        if (layer == 0 && (t & 63) == 63 && t < 448) {
            const int c = (t >> 6) + 1;            // chunks 1..7
            const int slot = c & 1;
            const int b = jb;                       // own batch row
            __syncthreads();                        // gates done; safe to alias PfF
            float* tileF = PfF;                     // [64][65]
#pragma unroll 1
            for (int i = 0; i < 9; ++i) {
                const int f0 = i * 64;
#pragma unroll
                for (int rr = 0; rr < 8; ++rr) {
                    const int fl = (tid >> 6) + rr * 8;
                    const int tt2 = tid & 63;
                    const int f = f0 + fl;
                    tileF[fl * 65 + tt2] = (f < FF) ? x[((size_t)b * FF + f) * TT + (size_t)c * 64 + tt2] : 0.f;
                }
                __syncthreads();
                if (tid < 256) {
                    const int q = tid & 3, tt2 = tid >> 2;
                    const int fq = f0 + q * 16;
                    if (fq < KX) {
                        const int it2 = fq >> 5, hf = (fq >> 4) & 1;
                        s16x8 vh0, vl0, vh1, vl1;
#pragma unroll
                        for (int m = 0; m < 8; ++m) {
                            short hi, lo; bfsplit(tileF[(q * 16 + m) * 65 + tt2], hi, lo);
                            vh0[m] = hi; vl0[m] = lo;
                        }
#pragma unroll
                        for (int m = 0; m < 8; ++m) {
                            short hi, lo; bfsplit(tileF[(q * 16 + 8 + m) * 65 + tt2], hi, lo);
                            vh1[m] = hi; vl1[m] = lo;
                        }
                        size_t tb = (size_t)slot * XCH2 + (size_t)tt2 * XFT
                                  + (size_t)(it2 * 4 + (b >> 4)) * 512
                                  + (size_t)(b & 15) * 8 + hf * 4;
                        astore8(Xh + tb,       lo4(vh0));
                        astore8(Xh + tb + 128, hi4(vh0));
                        astore8(Xh + tb + 256, lo4(vh1));
                        astore8(Xh + tb + 384, hi4(vh1));
                        astore8(Xl + tb,       lo4(vl0));
                        astore8(Xl + tb + 128, hi4(vl0));
                        astore8(Xl + tb + 256, lo4(vl1));
                        astore8(Xl + tb + 384, hi4(vl1));
                    }
                }
                __syncthreads();
            }
            asm volatile("s_waitcnt vmcnt(0)" ::: "memory");   // drain x stores
            __syncthreads();   // all waves drained before tid0 flags
        }

        // ---- flag completion of step t ----
        if (tid == 0) {
            asm volatile("s_waitcnt vmcnt(0)" ::: "memory");   // drain wave0 h stores
            __hip_atomic_store(&arrive[bid * 32], (unsigned)(t + 1),
                               __ATOMIC_RELAXED, __HIP_MEMORY_SCOPE_AGENT);
        }
    }
}

// ---------- final FCs (fc1 reads lane-contiguous fragment h3) ----------
__global__ __launch_bounds__(256) void fc1_k(
    const short* __restrict__ H3h, const short* __restrict__ H3l,
    const float* __restrict__ W, const float* __restrict__ bias,
    float* __restrict__ hid)
{
    const int lane = (int)threadIdx.x & 63;                  // = b
    const int wv = __builtin_amdgcn_readfirstlane((int)threadIdx.x >> 6);
    const int n = (int)blockIdx.x * 4 + wv;                  // 0..511
    const int bt = lane >> 4, rl = lane & 15;
    float acc = 0.f;
    const float* wr = W + (size_t)n * HH;
    for (int it = 0; it < 16; ++it) {
#pragma unroll
        for (int hf = 0; hf < 2; ++hf) {
#pragma unroll
            for (int g4 = 0; g4 < 4; ++g4) {
                const int k = it * 32 + hf * 16 + g4 * 4;
                const int fa = ((it * 4 + bt) * 64 + g4 * 16 + rl) * 8 + hf * 4;
                s16x4 vh = *(const s16x4*)(H3h + fa);
                s16x4 vl = *(const s16x4*)(H3l + fa);
#pragma unroll
                for (int i = 0; i < 4; ++i)
                    acc = fmaf(bf2f(vh[i]) + bf2f(vl[i]), wr[k + i], acc);
            }
        }
    }
    acc += bias[n];
    hid[(size_t)lane * HH + n] = fmaxf(acc, 0.f);
}

__global__ __launch_bounds__(256) void fc2_k(
    const float* __restrict__ hid, const float* __restrict__ W,
    const float* __restrict__ bias, float* __restrict__ out)
{
    const int lane = (int)threadIdx.x & 63;                  // = b
    const int wv = __builtin_amdgcn_readfirstlane((int)threadIdx.x >> 6);
    const int n = (int)blockIdx.x * 4 + wv;                  // 0..515
    if (n >= FF) return;
    float acc = 0.f;
    const float* wr = W + (size_t)n * HH;
    const float* hp = hid + (size_t)lane * HH;
    for (int k = 0; k < HH; k += 8) {
        float4 a = *(const float4*)(hp + k);
        float4 b = *(const float4*)(hp + k + 4);
        acc = fmaf(a.x, wr[k+0], acc); acc = fmaf(a.y, wr[k+1], acc);
        acc = fmaf(a.z, wr[k+2], acc); acc = fmaf(a.w, wr[k+3], acc);
        acc = fmaf(b.x, wr[k+4], acc); acc = fmaf(b.y, wr[k+5], acc);
        acc = fmaf(b.z, wr[k+6], acc); acc = fmaf(b.w, wr[k+7], acc);
    }
    out[(size_t)lane * FF + n] = acc + bias[n];
}

extern "C" void kernel_launch(void* const* d_in, const int* in_sizes, int n_in,
                              void* d_out, int out_size, void* d_ws, size_t ws_size,
                              hipStream_t stream)
{
    const float* x     = (const float*)d_in[0];
    const float* Wih1  = (const float*)d_in[1];
    const float* Whh1  = (const float*)d_in[2];
    const float* bih1  = (const float*)d_in[3];
    const float* bhh1  = (const float*)d_in[4];
    const float* Wih2  = (const float*)d_in[5];
    const float* Whh2  = (const float*)d_in[6];
    const float* bih2  = (const float*)d_in[7];
    const float* bhh2  = (const float*)d_in[8];
    const float* Wih3  = (const float*)d_in[9];
    const float* Whh3  = (const float*)d_in[10];
    const float* bih3  = (const float*)d_in[11];
    const float* bhh3  = (const float*)d_in[12];
    const float* fc1_w = (const float*)d_in[13];
    const float* fc1_b = (const float*)d_in[14];
    const float* fc2_w = (const float*)d_in[15];
    const float* fc2_b = (const float*)d_in[16];

    char* p = (char*)d_ws;
    unsigned* arrive = (unsigned*)p;                       // GRID*32 u32 slots
    p = (char*)d_ws + 32768;            // barrier region (memset each call)
    float* cT   = (float*)p;            p += (size_t)3 * HH * BB * 4;
    float* hid  = (float*)p;            p += (size_t)HH * BB * 4;
    float* bsum = (float*)p;            p += 6144 * 4;
    short* Hh   = (short*)p;            p += (size_t)12 * SBH * 2;   // 3 layers x 4 slots
    short* Hl   = (short*)p;            p += (size_t)12 * SBH * 2;
    short* Xh   = (short*)p;            p += (size_t)2 * XCH2 * 2;
    short* Xl   = (short*)p;            p += (size_t)2 * XCH2 * 2;
    short* Bh   = (short*)p;            p += (size_t)TOTB * 2;
    short* Bl   = (short*)p;            p += (size_t)TOTB * 2;
    if ((size_t)(p - (char*)d_ws) > ws_size) return;

    hipMemsetAsync(d_ws, 0, 32768, stream);
    prep_state_h<<<384, 256, 0, stream>>>(
        (const float*)d_in[17], (const float*)d_in[19], (const float*)d_in[21], Hh, Hl);
    prep_state_c<<<24, 256, 0, stream>>>(
        (const float*)d_in[18], (const float*)d_in[20], (const float*)d_in[22], cT);
    prep_bias<<<24, 256, 0, stream>>>(bih1, bhh1, bih2, bhh2, bih3, bhh3, bsum);
    prep_blob<<<TOTB / 256, 256, 0, stream>>>(Wih1, Whh1, Wih2, Whh2, Wih3, Whh3, Bh, Bl);
    prep_x<<<576, 256, 0, stream>>>(x, Xh, Xl);

    lstm_persist<<<GRID, 512, 0, stream>>>(x, Bh, Bl, Xh, Xl, Hh, Hl, bsum, cT, arrive);

    // final h3 = h_2[511] -> slot (511+1)&3 = 0 -> layer2 slot0 = +8*SBH
    fc1_k<<<128, 256, 0, stream>>>(Hh + (size_t)8 * SBH, Hl + (size_t)8 * SBH,
                                   fc1_w, fc1_b, hid);
    fc2_k<<<129, 256, 0, stream>>>(hid, fc2_w, fc2_b, (float*)d_out);
}

// Round 20
// 3461.131 us; speedup vs baseline: 1.2590x; 1.2590x over previous
//
#include <hip/hip_runtime.h>
#include <math.h>

// 3-layer LSTM (B=64,H=512,T=512,F=513) + FC(512)->ReLU->FC(513).
// R19 = R16 (persistent, register-resident split-bf16 MFMA weights, fence-free
//  MALL-coherent exchange, fragment-linear h AND x, 16B coherent loads,
//  per-group dataflow flags, 4-slot h ring, 8-wave K-split; R18's explicit
//  pipelining reverted - null) + two sync refinements:
//  (1) FINE-GRAINED PHASE POLLS: a wave's 4 k-tiles are produced by exactly
//      16 consecutive blocks (base=(wv&3)*16); poll those 16 flags, not 64.
//  (2) WAR PREPOLL: downstream>=t-2 checked at TOP of step (overlapped with
//      other waves' compute) instead of after gates on the critical path.

#define BB 64
#define HH 512
#define TT 512
#define FF 513
#define KX 544                 // padded x-K (17 tiles of 32)
#define KT1 33                 // L1 k-tiles (17 x + 16 h)
#define KT23 32
#define SBH 32768              // shorts per h slot (64*512)
#define XFT 34816              // shorts per x timestep (17*4*512)
#define XCH2 (64 * XFT)        // shorts per x ring slot: 2,228,224
#define OFF2 2162688
#define OFF3 4259840
#define TOTB 6356992
#define GRID 192
#define SPIN_CAP 5000000       // watchdog; never hit on happy path

typedef __attribute__((ext_vector_type(8))) short s16x8;
typedef __attribute__((ext_vector_type(4))) short s16x4;
typedef __attribute__((ext_vector_type(4))) float f32x4;

#define MFB(a, b, c) __builtin_amdgcn_mfma_f32_16x16x32_bf16(a, b, c, 0, 0, 0)

// 8x 16B coherent loads (bypass L1+L2, served from MALL) + one wait.
#define LOAD16X8(a0,a1,a2,a3,a4,a5,a6,a7,p0,p1,p2,p3,p4,p5,p6,p7)       \
    asm volatile(                                                        \
        "global_load_dwordx4 %0, %8, off sc0 sc1\n\t"                    \
        "global_load_dwordx4 %1, %9, off sc0 sc1\n\t"                    \
        "global_load_dwordx4 %2, %10, off sc0 sc1\n\t"                   \
        "global_load_dwordx4 %3, %11, off sc0 sc1\n\t"                   \
        "global_load_dwordx4 %4, %12, off sc0 sc1\n\t"                   \
        "global_load_dwordx4 %5, %13, off sc0 sc1\n\t"                   \
        "global_load_dwordx4 %6, %14, off sc0 sc1\n\t"                   \
        "global_load_dwordx4 %7, %15, off sc0 sc1\n\t"                   \
        "s_waitcnt vmcnt(0)"                                             \
        : "=&v"(a0), "=&v"(a1), "=&v"(a2), "=&v"(a3),                    \
          "=&v"(a4), "=&v"(a5), "=&v"(a6), "=&v"(a7)                     \
        : "v"(p0), "v"(p1), "v"(p2), "v"(p3),                            \
          "v"(p4), "v"(p5), "v"(p6), "v"(p7)                             \
        : "memory")

__device__ __forceinline__ float sigf(float x) { return 1.0f / (1.0f + expf(-x)); }

__device__ __forceinline__ float bf2f(short s) {
    return __uint_as_float(((unsigned)(unsigned short)s) << 16);
}
__device__ __forceinline__ short f2bf(float w) {   // RNE
    unsigned u = __float_as_uint(w);
    return (short)((u + 0x7fff + ((u >> 16) & 1)) >> 16);
}
__device__ __forceinline__ void bfsplit(float w, short& hi, short& lo) {
    hi = f2bf(w);
    lo = f2bf(w - bf2f(hi));
}

// ---- MALL write-through 8B stores (agent-scope relaxed atomics) ----
__device__ __forceinline__ void astore8(short* p, s16x4 v) {
    union { unsigned long long u; s16x4 s; } c; c.s = v;
    __hip_atomic_store((unsigned long long*)p, c.u,
                       __ATOMIC_RELAXED, __HIP_MEMORY_SCOPE_AGENT);
}
__device__ __forceinline__ s16x4 lo4(s16x8 v) {
    s16x4 r; r[0]=v[0]; r[1]=v[1]; r[2]=v[2]; r[3]=v[3]; return r;
}
__device__ __forceinline__ s16x4 hi4(s16x8 v) {
    s16x4 r; r[0]=v[4]; r[1]=v[5]; r[2]=v[6]; r[3]=v[7]; return r;
}

// Lane-contiguous fragment-blob address for element (b, k):
__device__ __forceinline__ int hfrag_addr(int b, int k) {
    int it = k >> 5, o32 = k & 31;
    int half = o32 >> 4, w = o32 & 15;
    int g = w >> 2, i = w & 3;
    int bt = b >> 4, rl = b & 15;
    return ((it * 4 + bt) * 64 + g * 16 + rl) * 8 + half * 4 + i;
}

// ---------- prep: initial h -> lane-contiguous fragment blobs, slot 0 ----------
__global__ __launch_bounds__(256) void prep_state_h(
    const float* __restrict__ h1, const float* __restrict__ h2,
    const float* __restrict__ h3, short* __restrict__ Hh, short* __restrict__ Hl)
{
    int idx = blockIdx.x * 256 + threadIdx.x;          // 3*32768
    int l = idx >> 15, e = idx & 32767;
    int b = e >> 9, u = e & 511;
    const float* s = l == 0 ? h1 : l == 1 ? h2 : h3;
    short hi, lo; bfsplit(s[e], hi, lo);
    int fa = hfrag_addr(b, u);
    Hh[(size_t)(l * 4) * SBH + fa] = hi;               // 4-slot ring, slot 0
    Hl[(size_t)(l * 4) * SBH + fa] = lo;
}

// ---------- prep: initial c transpose [b][u] -> cT[l][u][b] ----------
__global__ __launch_bounds__(256) void prep_state_c(
    const float* __restrict__ c1, const float* __restrict__ c2,
    const float* __restrict__ c3, float* __restrict__ cT)
{
    __shared__ float tile[64][65];
    int l = blockIdx.x >> 3, ut = blockIdx.x & 7;
    const float* s = l == 0 ? c1 : l == 1 ? c2 : c3;
    int u0 = ut * 64, tid = threadIdx.x;
#pragma unroll
    for (int p = 0; p < 16; ++p) {
        int b = p * 4 + (tid >> 6), u = tid & 63;
        tile[u][b] = s[(size_t)b * HH + u0 + u];
    }
    __syncthreads();
#pragma unroll
    for (int p = 0; p < 16; ++p) {
        int ul = p * 4 + (tid >> 6), b = tid & 63;
        cT[(size_t)l * (HH * BB) + (size_t)(u0 + ul) * BB + b] = tile[ul][b];
    }
}

// ---------- prep: bias sums, gate-interleaved j' = 4u+g ----------
__global__ __launch_bounds__(256) void prep_bias(
    const float* __restrict__ bi1, const float* __restrict__ bh1,
    const float* __restrict__ bi2, const float* __restrict__ bh2,
    const float* __restrict__ bi3, const float* __restrict__ bh3,
    float* __restrict__ bsum)
{
    int idx = blockIdx.x * 256 + threadIdx.x;          // 3*2048
    if (idx >= 6144) return;
    int l = idx >> 11, jq = idx & 2047;
    int u = jq >> 2, g = jq & 3;
    const float* bi = l == 0 ? bi1 : l == 1 ? bi2 : bi3;
    const float* bh = l == 0 ? bh1 : l == 1 ? bh2 : bh3;
    bsum[idx] = bi[g * HH + u] + bh[g * HH + u];
}

// ---------- prep: weight blobs (fragment-linear, split hi/lo) ----------
__global__ __launch_bounds__(256) void prep_blob(
    const float* __restrict__ Wih1, const float* __restrict__ Whh1,
    const float* __restrict__ Wih2, const float* __restrict__ Whh2,
    const float* __restrict__ Wih3, const float* __restrict__ Whh3,
    short* __restrict__ Bh, short* __restrict__ Bl)
{
    int idx = blockIdx.x * 256 + threadIdx.x;          // TOTB exact
    int l, e, KTl;
    if (idx < OFF2)      { l = 0; e = idx;        KTl = KT1;  }
    else if (idx < OFF3) { l = 1; e = idx - OFF2; KTl = KT23; }
    else                 { l = 2; e = idx - OFF3; KTl = KT23; }
    int jtkt = e >> 9, r = e & 511;
    int lane = r >> 3, i = r & 7;
    int jt = jtkt / KTl, kt = jtkt - jt * KTl;
    int n = lane & 15, g = (lane >> 4) & 3;
    int jq = jt * 16 + n;
    int u = jq >> 2, gate = jq & 3;
    int row = gate * HH + u;
    int kk = kt * 32 + ((i < 4) ? (g * 4 + i) : (16 + g * 4 + (i - 4)));
    float w;
    if (l == 0) {
        if (kk < KX) w = (kk < FF) ? Wih1[(size_t)row * FF + kk] : 0.f;
        else         w = Whh1[(size_t)row * HH + (kk - KX)];
    } else if (l == 1) {
        w = (kk < HH) ? Wih2[(size_t)row * HH + kk] : Whh2[(size_t)row * HH + kk - HH];
    } else {
        w = (kk < HH) ? Wih3[(size_t)row * HH + kk] : Whh3[(size_t)row * HH + kk - HH];
    }
    short hi, lo; bfsplit(w, hi, lo);
    Bh[idx] = hi; Bl[idx] = lo;
}

// ---------- prep: x chunk 0 -> FRAGMENT-LINEAR slot 0 ----------
__global__ __launch_bounds__(256) void prep_x(
    const float* __restrict__ x, short* __restrict__ Xh, short* __restrict__ Xl)
{
    __shared__ float tile[64][65];
    int b = blockIdx.x / 9, fblk = blockIdx.x % 9;
    int f0 = fblk * 64, tid = threadIdx.x;
#pragma unroll
    for (int p = 0; p < 16; ++p) {
        int fl = (tid >> 6) + p * 4, tt = tid & 63;
        int f = f0 + fl;
        tile[fl][tt] = (f < FF) ? x[((size_t)b * FF + f) * TT + tt] : 0.f;
    }
    __syncthreads();
    {
        int q = tid & 3, tt = tid >> 2;
        int fq = f0 + q * 16;
        if (fq < KX) {
            int it = fq >> 5, hf = (fq >> 4) & 1;
            s16x8 vh0, vl0, vh1, vl1;
#pragma unroll
            for (int m = 0; m < 8; ++m) {
                short hi, lo; bfsplit(tile[q * 16 + m][tt], hi, lo);
                vh0[m] = hi; vl0[m] = lo;
            }
#pragma unroll
            for (int m = 0; m < 8; ++m) {
                short hi, lo; bfsplit(tile[q * 16 + 8 + m][tt], hi, lo);
                vh1[m] = hi; vl1[m] = lo;
            }
            size_t tb = (size_t)tt * XFT
                      + (size_t)(it * 4 + (b >> 4)) * 512 + (size_t)(b & 15) * 8 + hf * 4;
            *(s16x4*)(Xh + tb      ) = lo4(vh0);
            *(s16x4*)(Xh + tb + 128) = hi4(vh0);
            *(s16x4*)(Xh + tb + 256) = lo4(vh1);
            *(s16x4*)(Xh + tb + 384) = hi4(vh1);
            *(s16x4*)(Xl + tb      ) = lo4(vl0);
            *(s16x4*)(Xl + tb + 128) = hi4(vl0);
            *(s16x4*)(Xl + tb + 256) = lo4(vl1);
            *(s16x4*)(Xl + tb + 384) = hi4(vl1);
        }
    }
}

// ---------- THE persistent kernel (8 waves) ----------
__global__ __launch_bounds__(512, 1) void lstm_persist(
    const float* __restrict__ x,
    const short* __restrict__ Bh, const short* __restrict__ Bl,
    short* __restrict__ Xh, short* __restrict__ Xl,
    short* __restrict__ Hh, short* __restrict__ Hl,   // [3][4 slots][SBH]
    const float* __restrict__ bsum, const float* __restrict__ cTin,
    unsigned* __restrict__ arrive)   // [GRID * 32] (128B-padded slots)
{
    __shared__ float PfF[8 * 32 * 65];     // 66560 B; aliased as x-tile [64][65]
    __shared__ float cLDS[8 * 64];
    __shared__ float biasLDS[32];
    __shared__ short hstH[64 * 8];
    __shared__ short hstL[64 * 8];

    const int bid = (int)blockIdx.x;
    const int layer = bid >> 6;            // 0..2
    const int jb = bid & 63;               // 0..63 -> j' cols [jb*32, jb*32+32)
    const int tid = (int)threadIdx.x;
    const int lane = tid & 63;
    const int wv = __builtin_amdgcn_readfirstlane(tid >> 6);   // 0..7
    const int rl = lane & 15, g = lane >> 4;
    const int u0 = jb * 8;

    // per-wave K split: waves 0-3 = phase A, waves 4-7 = phase B
    int kt0, ktn;
    if (layer == 0) {
        if (wv < 4) { kt0 = (wv == 0) ? 0 : 5 + 4 * (wv - 1); ktn = (wv == 0) ? 5 : 4; }
        else        { kt0 = 17 + (wv - 4) * 4; ktn = 4; }
    } else {
        if (wv < 4) { kt0 = wv * 4; ktn = 4; }
        else        { kt0 = 16 + (wv - 4) * 4; ktn = 4; }
    }
    const int KTl = (layer == 0) ? KT1 : KT23;
    const size_t blobOff = (layer == 0) ? 0 : ((layer == 1) ? (size_t)OFF2 : (size_t)OFF3);

    // ---- weights -> registers (once): 2 jt x <=5 kt, hi+lo ----
    s16x8 WHr[2][5], WLr[2][5];
#pragma unroll
    for (int jj = 0; jj < 2; ++jj) {
        const int jtG = jb * 2 + jj;
#pragma unroll
        for (int it = 0; it < 5; ++it) {
            if (it < ktn) {
                size_t o = blobOff + ((size_t)(jtG * KTl + kt0 + it)) * 512 + lane * 8;
                WHr[jj][it] = *(const s16x8*)(Bh + o);
                WLr[jj][it] = *(const s16x8*)(Bl + o);
            }
        }
    }

    // ---- c slice + bias -> LDS (once) ----
    cLDS[tid] = cTin[(size_t)layer * (HH * BB) + (size_t)u0 * 64 + tid];
    if (tid < 32) biasLDS[tid] = bsum[layer * 2048 + jb * 32 + tid];
    __syncthreads();

    // producer-side fragment store geometry (block owns u0..u0+7)
    const int p_it = jb >> 2;
    const int p_o  = (jb & 3) * 8;
    const int p_hf = (p_o >= 16) ? 1 : 0;
    const int p_gA = (p_o & 8) ? 2 : 0;

    const int upGrp = (layer > 0) ? layer - 1 : 0;
    const int pollBase = (wv & 3) * 16;     // 16 producer blocks of this wave's k-tiles

    for (int t = 0; t < TT; ++t) {
        // ---- per-wave selective wait (fine-grained: only the 16 producers) ----
        {
            int grp, thr; bool fine;
            if (wv < 4) {
                if (layer == 0) { grp = 0;     thr = t & ~63; fine = false; }  // x chunk
                else            { grp = upGrp; thr = t + 1;   fine = true;  }  // h_up[t]
            } else {
                grp = layer; thr = t; fine = true;                             // own h[t-1]
            }
            if (thr > 0) {
                const int fidx = fine ? (grp * 64 + pollBase + (lane & 15))
                                      : (grp * 64 + lane);
                int guard = 0;
                for (;;) {
                    unsigned v = __hip_atomic_load(&arrive[fidx * 32],
                                  __ATOMIC_RELAXED, __HIP_MEMORY_SCOPE_AGENT);
                    if (__all((int)v >= thr)) break;
                    if (++guard > SPIN_CAP) break;   // degrade visibly
                    __builtin_amdgcn_s_sleep(1);
                }
            }
        }
        // ---- WAR prepoll (wave 0): downstream consumed slot we'll overwrite ----
        if (layer < 2 && tid < 64) {
            const int thr = t - 2;
            if (thr > 0) {
                int guard = 0;
                for (;;) {
                    unsigned v = __hip_atomic_load(&arrive[((layer + 1) * 64 + lane) * 32],
                                  __ATOMIC_RELAXED, __HIP_MEMORY_SCOPE_AGENT);
                    if (__all((int)v >= thr)) break;
                    if (++guard > SPIN_CAP) break;
                    __builtin_amdgcn_s_sleep(1);
                }
            }
        }

        // ---- A fragment base (x and h share one layout & load path) ----
        const short* fH; const short* fL; int itg0;
        if (layer == 0) {
            if (wv < 4) {
                size_t xb = (size_t)((t >> 6) & 1) * XCH2 + (size_t)(t & 63) * XFT;
                fH = Xh + xb; fL = Xl + xb; itg0 = kt0;
            } else {
                size_t hb = (size_t)(0 * 4 + (t & 3)) * SBH;       // own h[t-1]
                fH = Hh + hb; fL = Hl + hb; itg0 = kt0 - 17;
            }
        } else if (layer == 1) {
            size_t hb;
            if (wv < 4) { hb = (size_t)(0 * 4 + ((t + 1) & 3)) * SBH; itg0 = kt0; }      // h0[t]
            else        { hb = (size_t)(1 * 4 + (t & 3)) * SBH;       itg0 = kt0 - 16; } // h1[t-1]
            fH = Hh + hb; fL = Hl + hb;
        } else {
            size_t hb;
            if (wv < 4) { hb = (size_t)(1 * 4 + ((t + 1) & 3)) * SBH; itg0 = kt0; }      // h1[t]
            else        { hb = (size_t)(2 * 4 + (t & 3)) * SBH;       itg0 = kt0 - 16; } // h2[t-1]
            fH = Hh + hb; fL = Hl + hb;
        }

        f32x4 acc[2][4];
#pragma unroll
        for (int jj = 0; jj < 2; ++jj)
#pragma unroll
            for (int bt = 0; bt < 4; ++bt) acc[jj][bt] = (f32x4){0.f, 0.f, 0.f, 0.f};

#define DO_TILE(IT)                                                          \
        {                                                                    \
            s16x8 aH0, aH1, aH2, aH3, aL0, aL1, aL2, aL3;                    \
            const int fb = (itg0 + (IT)) * 4;                                \
            const short* pH0 = fH + (size_t)(fb + 0) * 512 + lane * 8;       \
            const short* pH1 = fH + (size_t)(fb + 1) * 512 + lane * 8;       \
            const short* pH2 = fH + (size_t)(fb + 2) * 512 + lane * 8;       \
            const short* pH3 = fH + (size_t)(fb + 3) * 512 + lane * 8;       \
            const short* pL0 = fL + (size_t)(fb + 0) * 512 + lane * 8;       \
            const short* pL1 = fL + (size_t)(fb + 1) * 512 + lane * 8;       \
            const short* pL2 = fL + (size_t)(fb + 2) * 512 + lane * 8;       \
            const short* pL3 = fL + (size_t)(fb + 3) * 512 + lane * 8;       \
            LOAD16X8(aH0, aH1, aH2, aH3, aL0, aL1, aL2, aL3,                 \
                     pH0, pH1, pH2, pH3, pL0, pL1, pL2, pL3);                \
            _Pragma("unroll")                                                \
            for (int jj = 0; jj < 2; ++jj) {                                 \
                acc[jj][0] = MFB(aH0, WHr[jj][IT], acc[jj][0]);              \
                acc[jj][0] = MFB(aL0, WHr[jj][IT], acc[jj][0]);              \
                acc[jj][0] = MFB(aH0, WLr[jj][IT], acc[jj][0]);              \
                acc[jj][1] = MFB(aH1, WHr[jj][IT], acc[jj][1]);              \
                acc[jj][1] = MFB(aL1, WHr[jj][IT], acc[jj][1]);              \
                acc[jj][1] = MFB(aH1, WLr[jj][IT], acc[jj][1]);              \
                acc[jj][2] = MFB(aH2, WHr[jj][IT], acc[jj][2]);              \
                acc[jj][2] = MFB(aL2, WHr[jj][IT], acc[jj][2]);              \
                acc[jj][2] = MFB(aH2, WLr[jj][IT], acc[jj][2]);              \
                acc[jj][3] = MFB(aH3, WHr[jj][IT], acc[jj][3]);              \
                acc[jj][3] = MFB(aL3, WHr[jj][IT], acc[jj][3]);              \
                acc[jj][3] = MFB(aH3, WLr[jj][IT], acc[jj][3]);              \
            }                                                                \
        }

        DO_TILE(0)
        DO_TILE(1)
        DO_TILE(2)
        DO_TILE(3)
        if (layer == 0 && wv == 0) DO_TILE(4)   // L0 wave 0 owns 5 k-tiles
#undef DO_TILE

        // ---- partial reduce across 8 waves ----
        __syncthreads();   // prev step's readers of PfF done
#pragma unroll
        for (int jj = 0; jj < 2; ++jj)
#pragma unroll
            for (int bt = 0; bt < 4; ++bt)
#pragma unroll
                for (int r = 0; r < 4; ++r)
                    PfF[(wv * 32 + jj * 16 + rl) * 65 + bt * 16 + g * 4 + r] = acc[jj][bt][r];
        __syncthreads();

        {   // gates + pointwise: 512 threads cover (ul 0..7) x (b 0..63)
            const int half = tid >> 8;             // 0..1
            const int r5 = tid & 255;
            const int ul = r5 >> 5, bl = r5 & 31;
            const int b = half * 32 + bl;
            float G[4];
#pragma unroll
            for (int gi = 0; gi < 4; ++gi) {
                const int jl = ul * 4 + gi;
                float v = 0.f;
#pragma unroll
                for (int w8 = 0; w8 < 8; ++w8)
                    v += PfF[(w8 * 32 + jl) * 65 + b];
                G[gi] = v + biasLDS[jl];
            }
            float cold = cLDS[ul * 64 + b];
            float cn = sigf(G[1]) * cold + sigf(G[0]) * tanhf(G[2]);
            float hn = sigf(G[3]) * tanhf(cn);
            cLDS[ul * 64 + b] = cn;
            short hi, lo; bfsplit(hn, hi, lo);
            hstH[b * 8 + ul] = hi;
            hstL[b * 8 + ul] = lo;
        }
        __syncthreads();

        if (tid < 64) {
            // write h slice -> lane-contiguous blob slot (t+1)&3 (write-through)
            // (WAR for this slot was prepolled at top of step)
            const int b = tid, bt = b >> 4, prl = b & 15;
            const size_t base = (size_t)(layer * 4 + ((t + 1) & 3)) * SBH
                              + (size_t)(p_it * 4 + bt) * 512 + p_hf * 4;
            const size_t aA = base + (size_t)(p_gA * 16 + prl) * 8;
            const size_t aB = base + (size_t)((p_gA + 1) * 16 + prl) * 8;
            s16x8 vh = *(const s16x8*)(hstH + b * 8);
            s16x8 vl = *(const s16x8*)(hstL + b * 8);
            astore8(Hh + aA, lo4(vh));
            astore8(Hh + aB, hi4(vh));
            astore8(Hl + aA, lo4(vl));
            astore8(Hl + aB, hi4(vl));
        }

        // ---- x-transpose of NEXT chunk at end of steps t%64==63 (layer 0) ----
        if (layer == 0 && (t & 63) == 63 && t < 448) {
            const int c = (t >> 6) + 1;            // chunks 1..7
            const int slot = c & 1;
            const int b = jb;                       // own batch row
            __syncthreads();                        // gates done; safe to alias PfF
            float* tileF = PfF;                     // [64][65]
#pragma unroll 1
            for (int i = 0; i < 9; ++i) {
                const int f0 = i * 64;
#pragma unroll
                for (int rr = 0; rr < 8; ++rr) {
                    const int fl = (tid >> 6) + rr * 8;
                    const int tt2 = tid & 63;
                    const int f = f0 + fl;
                    tileF[fl * 65 + tt2] = (f < FF) ? x[((size_t)b * FF + f) * TT + (size_t)c * 64 + tt2] : 0.f;
                }
                __syncthreads();
                if (tid < 256) {
                    const int q = tid & 3, tt2 = tid >> 2;
                    const int fq = f0 + q * 16;
                    if (fq < KX) {
                        const int it2 = fq >> 5, hf = (fq >> 4) & 1;
                        s16x8 vh0, vl0, vh1, vl1;
#pragma unroll
                        for (int m = 0; m < 8; ++m) {
                            short hi, lo; bfsplit(tileF[(q * 16 + m) * 65 + tt2], hi, lo);
                            vh0[m] = hi; vl0[m] = lo;
                        }
#pragma unroll
                        for (int m = 0; m < 8; ++m) {
                            short hi, lo; bfsplit(tileF[(q * 16 + 8 + m) * 65 + tt2], hi, lo);
                            vh1[m] = hi; vl1[m] = lo;
                        }
                        size_t tb = (size_t)slot * XCH2 + (size_t)tt2 * XFT
                                  + (size_t)(it2 * 4 + (b >> 4)) * 512
                                  + (size_t)(b & 15) * 8 + hf * 4;
                        astore8(Xh + tb,       lo4(vh0));
                        astore8(Xh + tb + 128, hi4(vh0));
                        astore8(Xh + tb + 256, lo4(vh1));
                        astore8(Xh + tb + 384, hi4(vh1));
                        astore8(Xl + tb,       lo4(vl0));
                        astore8(Xl + tb + 128, hi4(vl0));
                        astore8(Xl + tb + 256, lo4(vl1));
                        astore8(Xl + tb + 384, hi4(vl1));
                    }
                }
                __syncthreads();
            }
            asm volatile("s_waitcnt vmcnt(0)" ::: "memory");   // drain x stores
            __syncthreads();   // all waves drained before tid0 flags
        }

        // ---- flag completion of step t ----
        if (tid == 0) {
            asm volatile("s_waitcnt vmcnt(0)" ::: "memory");   // drain wave0 h stores
            __hip_atomic_store(&arrive[bid * 32], (unsigned)(t + 1),
                               __ATOMIC_RELAXED, __HIP_MEMORY_SCOPE_AGENT);
        }
    }
}

// ---------- final FCs (fc1 reads lane-contiguous fragment h3) ----------
__global__ __launch_bounds__(256) void fc1_k(
    const short* __restrict__ H3h, const short* __restrict__ H3l,
    const float* __restrict__ W, const float* __restrict__ bias,
    float* __restrict__ hid)
{
    const int lane = (int)threadIdx.x & 63;                  // = b
    const int wv = __builtin_amdgcn_readfirstlane((int)threadIdx.x >> 6);
    const int n = (int)blockIdx.x * 4 + wv;                  // 0..511
    const int bt = lane >> 4, rl = lane & 15;
    float acc = 0.f;
    const float* wr = W + (size_t)n * HH;
    for (int it = 0; it < 16; ++it) {
#pragma unroll
        for (int hf = 0; hf < 2; ++hf) {
#pragma unroll
            for (int g4 = 0; g4 < 4; ++g4) {
                const int k = it * 32 + hf * 16 + g4 * 4;
                const int fa = ((it * 4 + bt) * 64 + g4 * 16 + rl) * 8 + hf * 4;
                s16x4 vh = *(const s16x4*)(H3h + fa);
                s16x4 vl = *(const s16x4*)(H3l + fa);
#pragma unroll
                for (int i = 0; i < 4; ++i)
                    acc = fmaf(bf2f(vh[i]) + bf2f(vl[i]), wr[k + i], acc);
            }
        }
    }
    acc += bias[n];
    hid[(size_t)lane * HH + n] = fmaxf(acc, 0.f);
}

__global__ __launch_bounds__(256) void fc2_k(
    const float* __restrict__ hid, const float* __restrict__ W,
    const float* __restrict__ bias, float* __restrict__ out)
{
    const int lane = (int)threadIdx.x & 63;                  // = b
    const int wv = __builtin_amdgcn_readfirstlane((int)threadIdx.x >> 6);
    const int n = (int)blockIdx.x * 4 + wv;                  // 0..515
    if (n >= FF) return;
    float acc = 0.f;
    const float* wr = W + (size_t)n * HH;
    const float* hp = hid + (size_t)lane * HH;
    for (int k = 0; k < HH; k += 8) {
        float4 a = *(const float4*)(hp + k);
        float4 b = *(const float4*)(hp + k + 4);
        acc = fmaf(a.x, wr[k+0], acc); acc = fmaf(a.y, wr[k+1], acc);
        acc = fmaf(a.z, wr[k+2], acc); acc = fmaf(a.w, wr[k+3], acc);
        acc = fmaf(b.x, wr[k+4], acc); acc = fmaf(b.y, wr[k+5], acc);
        acc = fmaf(b.z, wr[k+6], acc); acc = fmaf(b.w, wr[k+7], acc);
    }
    out[(size_t)lane * FF + n] = acc + bias[n];
}

extern "C" void kernel_launch(void* const* d_in, const int* in_sizes, int n_in,
                              void* d_out, int out_size, void* d_ws, size_t ws_size,
                              hipStream_t stream)
{
    const float* x     = (const float*)d_in[0];
    const float* Wih1  = (const float*)d_in[1];
    const float* Whh1  = (const float*)d_in[2];
    const float* bih1  = (const float*)d_in[3];
    const float* bhh1  = (const float*)d_in[4];
    const float* Wih2  = (const float*)d_in[5];
    const float* Whh2  = (const float*)d_in[6];
    const float* bih2  = (const float*)d_in[7];
    const float* bhh2  = (const float*)d_in[8];
    const float* Wih3  = (const float*)d_in[9];
    const float* Whh3  = (const float*)d_in[10];
    const float* bih3  = (const float*)d_in[11];
    const float* bhh3  = (const float*)d_in[12];
    const float* fc1_w = (const float*)d_in[13];
    const float* fc1_b = (const float*)d_in[14];
    const float* fc2_w = (const float*)d_in[15];
    const float* fc2_b = (const float*)d_in[16];

    char* p = (char*)d_ws;
    unsigned* arrive = (unsigned*)p;                       // GRID*32 u32 slots
    p = (char*)d_ws + 32768;            // barrier region (memset each call)
    float* cT   = (float*)p;            p += (size_t)3 * HH * BB * 4;
    float* hid  = (float*)p;            p += (size_t)HH * BB * 4;
    float* bsum = (float*)p;            p += 6144 * 4;
    short* Hh   = (short*)p;            p += (size_t)12 * SBH * 2;   // 3 layers x 4 slots
    short* Hl   = (short*)p;            p += (size_t)12 * SBH * 2;
    short* Xh   = (short*)p;            p += (size_t)2 * XCH2 * 2;
    short* Xl   = (short*)p;            p += (size_t)2 * XCH2 * 2;
    short* Bh   = (short*)p;            p += (size_t)TOTB * 2;
    short* Bl   = (short*)p;            p += (size_t)TOTB * 2;
    if ((size_t)(p - (char*)d_ws) > ws_size) return;

    hipMemsetAsync(d_ws, 0, 32768, stream);
    prep_state_h<<<384, 256, 0, stream>>>(
        (const float*)d_in[17], (const float*)d_in[19], (const float*)d_in[21], Hh, Hl);
    prep_state_c<<<24, 256, 0, stream>>>(
        (const float*)d_in[18], (const float*)d_in[20], (const float*)d_in[22], cT);
    prep_bias<<<24, 256, 0, stream>>>(bih1, bhh1, bih2, bhh2, bih3, bhh3, bsum);
    prep_blob<<<TOTB / 256, 256, 0, stream>>>(Wih1, Whh1, Wih2, Whh2, Wih3, Whh3, Bh, Bl);
    prep_x<<<576, 256, 0, stream>>>(x, Xh, Xl);

    lstm_persist<<<GRID, 512, 0, stream>>>(x, Bh, Bl, Xh, Xl, Hh, Hl, bsum, cT, arrive);

    // final h3 = h_2[511] -> slot (511+1)&3 = 0 -> layer2 slot0 = +8*SBH
    fc1_k<<<128, 256, 0, stream>>>(Hh + (size_t)8 * SBH, Hl + (size_t)8 * SBH,
                                   fc1_w, fc1_b, hid);
    fc2_k<<<129, 256, 0, stream>>>(hid, fc2_w, fc2_b, (float*)d_out);
}

// Round 21
// 3369.751 us; speedup vs baseline: 1.2931x; 1.0271x over previous
//
#include <hip/hip_runtime.h>
#include <math.h>

// 3-layer LSTM (B=64,H=512,T=512,F=513) + FC(512)->ReLU->FC(513).
// R20 = R19 (persistent, register-resident split-bf16 MFMA weights, fence-free
//  MALL-coherent exchange, fragment-linear h AND x, 16B coherent loads,
//  fine-grained phase polls, WAR prepoll, 4-slot h ring, 8-wave K-split)
//  with SINGLE-bf16 RECURRENT h (drop the whi*hlo product):
//  h stored/loaded as one bf16 blob -> h-path bytes and stores HALVED,
//  h-path MFMAs 12->8 per jj*tile. Weights keep hi+lo (exact); x keeps
//  hi+lo (non-recurrent, 17% of traffic). Error analysis: ~1.8e-4/step
//  zero-mean gate noise, contractive recurrence -> absmax ~5-8e-4 < 1.2e-3.

#define BB 64
#define HH 512
#define TT 512
#define FF 513
#define KX 544                 // padded x-K (17 tiles of 32)
#define KT1 33                 // L1 k-tiles (17 x + 16 h)
#define KT23 32
#define SBH 32768              // shorts per h slot (64*512)
#define XFT 34816              // shorts per x timestep (17*4*512)
#define XCH2 (64 * XFT)        // shorts per x ring slot: 2,228,224
#define OFF2 2162688
#define OFF3 4259840
#define TOTB 6356992
#define GRID 192
#define SPIN_CAP 5000000       // watchdog; never hit on happy path

typedef __attribute__((ext_vector_type(8))) short s16x8;
typedef __attribute__((ext_vector_type(4))) short s16x4;
typedef __attribute__((ext_vector_type(4))) float f32x4;

#define MFB(a, b, c) __builtin_amdgcn_mfma_f32_16x16x32_bf16(a, b, c, 0, 0, 0)

// 8x 16B coherent loads (bypass L1+L2, served from MALL) + one wait.
#define LOAD16X8(a0,a1,a2,a3,a4,a5,a6,a7,p0,p1,p2,p3,p4,p5,p6,p7)       \
    asm volatile(                                                        \
        "global_load_dwordx4 %0, %8, off sc0 sc1\n\t"                    \
        "global_load_dwordx4 %1, %9, off sc0 sc1\n\t"                    \
        "global_load_dwordx4 %2, %10, off sc0 sc1\n\t"                   \
        "global_load_dwordx4 %3, %11, off sc0 sc1\n\t"                   \
        "global_load_dwordx4 %4, %12, off sc0 sc1\n\t"                   \
        "global_load_dwordx4 %5, %13, off sc0 sc1\n\t"                   \
        "global_load_dwordx4 %6, %14, off sc0 sc1\n\t"                   \
        "global_load_dwordx4 %7, %15, off sc0 sc1\n\t"                   \
        "s_waitcnt vmcnt(0)"                                             \
        : "=&v"(a0), "=&v"(a1), "=&v"(a2), "=&v"(a3),                    \
          "=&v"(a4), "=&v"(a5), "=&v"(a6), "=&v"(a7)                     \
        : "v"(p0), "v"(p1), "v"(p2), "v"(p3),                            \
          "v"(p4), "v"(p5), "v"(p6), "v"(p7)                             \
        : "memory")

// 4x 16B coherent loads + one wait (single-bf16 h path).
#define LOAD16X4(a0,a1,a2,a3,p0,p1,p2,p3)                                \
    asm volatile(                                                        \
        "global_load_dwordx4 %0, %4, off sc0 sc1\n\t"                    \
        "global_load_dwordx4 %1, %5, off sc0 sc1\n\t"                    \
        "global_load_dwordx4 %2, %6, off sc0 sc1\n\t"                    \
        "global_load_dwordx4 %3, %7, off sc0 sc1\n\t"                    \
        "s_waitcnt vmcnt(0)"                                             \
        : "=&v"(a0), "=&v"(a1), "=&v"(a2), "=&v"(a3)                     \
        : "v"(p0), "v"(p1), "v"(p2), "v"(p3)                             \
        : "memory")

__device__ __forceinline__ float sigf(float x) { return 1.0f / (1.0f + expf(-x)); }

__device__ __forceinline__ float bf2f(short s) {
    return __uint_as_float(((unsigned)(unsigned short)s) << 16);
}
__device__ __forceinline__ short f2bf(float w) {   // RNE
    unsigned u = __float_as_uint(w);
    return (short)((u + 0x7fff + ((u >> 16) & 1)) >> 16);
}
__device__ __forceinline__ void bfsplit(float w, short& hi, short& lo) {
    hi = f2bf(w);
    lo = f2bf(w - bf2f(hi));
}

// ---- MALL write-through 8B stores (agent-scope relaxed atomics) ----
__device__ __forceinline__ void astore8(short* p, s16x4 v) {
    union { unsigned long long u; s16x4 s; } c; c.s = v;
    __hip_atomic_store((unsigned long long*)p, c.u,
                       __ATOMIC_RELAXED, __HIP_MEMORY_SCOPE_AGENT);
}
__device__ __forceinline__ s16x4 lo4(s16x8 v) {
    s16x4 r; r[0]=v[0]; r[1]=v[1]; r[2]=v[2]; r[3]=v[3]; return r;
}
__device__ __forceinline__ s16x4 hi4(s16x8 v) {
    s16x4 r; r[0]=v[4]; r[1]=v[5]; r[2]=v[6]; r[3]=v[7]; return r;
}

// Lane-contiguous fragment-blob address for element (b, k):
__device__ __forceinline__ int hfrag_addr(int b, int k) {
    int it = k >> 5, o32 = k & 31;
    int half = o32 >> 4, w = o32 & 15;
    int g = w >> 2, i = w & 3;
    int bt = b >> 4, rl = b & 15;
    return ((it * 4 + bt) * 64 + g * 16 + rl) * 8 + half * 4 + i;
}

// ---------- prep: initial h -> single-bf16 fragment blob, slot 0 ----------
__global__ __launch_bounds__(256) void prep_state_h(
    const float* __restrict__ h1, const float* __restrict__ h2,
    const float* __restrict__ h3, short* __restrict__ Hh)
{
    int idx = blockIdx.x * 256 + threadIdx.x;          // 3*32768
    int l = idx >> 15, e = idx & 32767;
    int b = e >> 9, u = e & 511;
    const float* s = l == 0 ? h1 : l == 1 ? h2 : h3;
    int fa = hfrag_addr(b, u);
    Hh[(size_t)(l * 4) * SBH + fa] = f2bf(s[e]);       // 4-slot ring, slot 0
}

// ---------- prep: initial c transpose [b][u] -> cT[l][u][b] ----------
__global__ __launch_bounds__(256) void prep_state_c(
    const float* __restrict__ c1, const float* __restrict__ c2,
    const float* __restrict__ c3, float* __restrict__ cT)
{
    __shared__ float tile[64][65];
    int l = blockIdx.x >> 3, ut = blockIdx.x & 7;
    const float* s = l == 0 ? c1 : l == 1 ? c2 : c3;
    int u0 = ut * 64, tid = threadIdx.x;
#pragma unroll
    for (int p = 0; p < 16; ++p) {
        int b = p * 4 + (tid >> 6), u = tid & 63;
        tile[u][b] = s[(size_t)b * HH + u0 + u];
    }
    __syncthreads();
#pragma unroll
    for (int p = 0; p < 16; ++p) {
        int ul = p * 4 + (tid >> 6), b = tid & 63;
        cT[(size_t)l * (HH * BB) + (size_t)(u0 + ul) * BB + b] = tile[ul][b];
    }
}

// ---------- prep: bias sums, gate-interleaved j' = 4u+g ----------
__global__ __launch_bounds__(256) void prep_bias(
    const float* __restrict__ bi1, const float* __restrict__ bh1,
    const float* __restrict__ bi2, const float* __restrict__ bh2,
    const float* __restrict__ bi3, const float* __restrict__ bh3,
    float* __restrict__ bsum)
{
    int idx = blockIdx.x * 256 + threadIdx.x;          // 3*2048
    if (idx >= 6144) return;
    int l = idx >> 11, jq = idx & 2047;
    int u = jq >> 2, g = jq & 3;
    const float* bi = l == 0 ? bi1 : l == 1 ? bi2 : bi3;
    const float* bh = l == 0 ? bh1 : l == 1 ? bh2 : bh3;
    bsum[idx] = bi[g * HH + u] + bh[g * HH + u];
}

// ---------- prep: weight blobs (fragment-linear, split hi/lo) ----------
__global__ __launch_bounds__(256) void prep_blob(
    const float* __restrict__ Wih1, const float* __restrict__ Whh1,
    const float* __restrict__ Wih2, const float* __restrict__ Whh2,
    const float* __restrict__ Wih3, const float* __restrict__ Whh3,
    short* __restrict__ Bh, short* __restrict__ Bl)
{
    int idx = blockIdx.x * 256 + threadIdx.x;          // TOTB exact
    int l, e, KTl;
    if (idx < OFF2)      { l = 0; e = idx;        KTl = KT1;  }
    else if (idx < OFF3) { l = 1; e = idx - OFF2; KTl = KT23; }
    else                 { l = 2; e = idx - OFF3; KTl = KT23; }
    int jtkt = e >> 9, r = e & 511;
    int lane = r >> 3, i = r & 7;
    int jt = jtkt / KTl, kt = jtkt - jt * KTl;
    int n = lane & 15, g = (lane >> 4) & 3;
    int jq = jt * 16 + n;
    int u = jq >> 2, gate = jq & 3;
    int row = gate * HH + u;
    int kk = kt * 32 + ((i < 4) ? (g * 4 + i) : (16 + g * 4 + (i - 4)));
    float w;
    if (l == 0) {
        if (kk < KX) w = (kk < FF) ? Wih1[(size_t)row * FF + kk] : 0.f;
        else         w = Whh1[(size_t)row * HH + (kk - KX)];
    } else if (l == 1) {
        w = (kk < HH) ? Wih2[(size_t)row * HH + kk] : Whh2[(size_t)row * HH + kk - HH];
    } else {
        w = (kk < HH) ? Wih3[(size_t)row * HH + kk] : Whh3[(size_t)row * HH + kk - HH];
    }
    short hi, lo; bfsplit(w, hi, lo);
    Bh[idx] = hi; Bl[idx] = lo;
}

// ---------- prep: x chunk 0 -> FRAGMENT-LINEAR slot 0 ----------
__global__ __launch_bounds__(256) void prep_x(
    const float* __restrict__ x, short* __restrict__ Xh, short* __restrict__ Xl)
{
    __shared__ float tile[64][65];
    int b = blockIdx.x / 9, fblk = blockIdx.x % 9;
    int f0 = fblk * 64, tid = threadIdx.x;
#pragma unroll
    for (int p = 0; p < 16; ++p) {
        int fl = (tid >> 6) + p * 4, tt = tid & 63;
        int f = f0 + fl;
        tile[fl][tt] = (f < FF) ? x[((size_t)b * FF + f) * TT + tt] : 0.f;
    }
    __syncthreads();
    {
        int q = tid & 3, tt = tid >> 2;
        int fq = f0 + q * 16;
        if (fq < KX) {
            int it = fq >> 5, hf = (fq >> 4) & 1;
            s16x8 vh0, vl0, vh1, vl1;
#pragma unroll
            for (int m = 0; m < 8; ++m) {
                short hi, lo; bfsplit(tile[q * 16 + m][tt], hi, lo);
                vh0[m] = hi; vl0[m] = lo;
            }
#pragma unroll
            for (int m = 0; m < 8; ++m) {
                short hi, lo; bfsplit(tile[q * 16 + 8 + m][tt], hi, lo);
                vh1[m] = hi; vl1[m] = lo;
            }
            size_t tb = (size_t)tt * XFT
                      + (size_t)(it * 4 + (b >> 4)) * 512 + (size_t)(b & 15) * 8 + hf * 4;
            *(s16x4*)(Xh + tb      ) = lo4(vh0);
            *(s16x4*)(Xh + tb + 128) = hi4(vh0);
            *(s16x4*)(Xh + tb + 256) = lo4(vh1);
            *(s16x4*)(Xh + tb + 384) = hi4(vh1);
            *(s16x4*)(Xl + tb      ) = lo4(vl0);
            *(s16x4*)(Xl + tb + 128) = hi4(vl0);
            *(s16x4*)(Xl + tb + 256) = lo4(vl1);
            *(s16x4*)(Xl + tb + 384) = hi4(vl1);
        }
    }
}

// ---------- THE persistent kernel (8 waves) ----------
__global__ __launch_bounds__(512, 1) void lstm_persist(
    const float* __restrict__ x,
    const short* __restrict__ Bh, const short* __restrict__ Bl,
    short* __restrict__ Xh, short* __restrict__ Xl,
    short* __restrict__ Hh,                     // [3][4 slots][SBH], single bf16
    const float* __restrict__ bsum, const float* __restrict__ cTin,
    unsigned* __restrict__ arrive)   // [GRID * 32] (128B-padded slots)
{
    __shared__ float PfF[8 * 32 * 65];     // 66560 B; aliased as x-tile [64][65]
    __shared__ float cLDS[8 * 64];
    __shared__ float biasLDS[32];
    __shared__ short hstH[64 * 8];

    const int bid = (int)blockIdx.x;
    const int layer = bid >> 6;            // 0..2
    const int jb = bid & 63;               // 0..63 -> j' cols [jb*32, jb*32+32)
    const int tid = (int)threadIdx.x;
    const int lane = tid & 63;
    const int wv = __builtin_amdgcn_readfirstlane(tid >> 6);   // 0..7
    const int rl = lane & 15, g = lane >> 4;
    const int u0 = jb * 8;

    // per-wave K split: waves 0-3 = phase A, waves 4-7 = phase B
    int kt0, ktn;
    if (layer == 0) {
        if (wv < 4) { kt0 = (wv == 0) ? 0 : 5 + 4 * (wv - 1); ktn = (wv == 0) ? 5 : 4; }
        else        { kt0 = 17 + (wv - 4) * 4; ktn = 4; }
    } else {
        if (wv < 4) { kt0 = wv * 4; ktn = 4; }
        else        { kt0 = 16 + (wv - 4) * 4; ktn = 4; }
    }
    const int KTl = (layer == 0) ? KT1 : KT23;
    const size_t blobOff = (layer == 0) ? 0 : ((layer == 1) ? (size_t)OFF2 : (size_t)OFF3);

    // ---- weights -> registers (once): 2 jt x <=5 kt, hi+lo ----
    s16x8 WHr[2][5], WLr[2][5];
#pragma unroll
    for (int jj = 0; jj < 2; ++jj) {
        const int jtG = jb * 2 + jj;
#pragma unroll
        for (int it = 0; it < 5; ++it) {
            if (it < ktn) {
                size_t o = blobOff + ((size_t)(jtG * KTl + kt0 + it)) * 512 + lane * 8;
                WHr[jj][it] = *(const s16x8*)(Bh + o);
                WLr[jj][it] = *(const s16x8*)(Bl + o);
            }
        }
    }

    // ---- c slice + bias -> LDS (once) ----
    cLDS[tid] = cTin[(size_t)layer * (HH * BB) + (size_t)u0 * 64 + tid];
    if (tid < 32) biasLDS[tid] = bsum[layer * 2048 + jb * 32 + tid];
    __syncthreads();

    // producer-side fragment store geometry (block owns u0..u0+7)
    const int p_it = jb >> 2;
    const int p_o  = (jb & 3) * 8;
    const int p_hf = (p_o >= 16) ? 1 : 0;
    const int p_gA = (p_o & 8) ? 2 : 0;

    const int upGrp = (layer > 0) ? layer - 1 : 0;
    const int pollBase = (wv & 3) * 16;     // 16 producer blocks of this wave's k-tiles

    for (int t = 0; t < TT; ++t) {
        // ---- per-wave selective wait (fine-grained: only the 16 producers) ----
        {
            int grp, thr; bool fine;
            if (wv < 4) {
                if (layer == 0) { grp = 0;     thr = t & ~63; fine = false; }  // x chunk
                else            { grp = upGrp; thr = t + 1;   fine = true;  }  // h_up[t]
            } else {
                grp = layer; thr = t; fine = true;                             // own h[t-1]
            }
            if (thr > 0) {
                const int fidx = fine ? (grp * 64 + pollBase + (lane & 15))
                                      : (grp * 64 + lane);
                int guard = 0;
                for (;;) {
                    unsigned v = __hip_atomic_load(&arrive[fidx * 32],
                                  __ATOMIC_RELAXED, __HIP_MEMORY_SCOPE_AGENT);
                    if (__all((int)v >= thr)) break;
                    if (++guard > SPIN_CAP) break;   // degrade visibly
                    __builtin_amdgcn_s_sleep(1);
                }
            }
        }
        // ---- WAR prepoll (wave 0): downstream consumed slot we'll overwrite ----
        if (layer < 2 && tid < 64) {
            const int thr = t - 2;
            if (thr > 0) {
                int guard = 0;
                for (;;) {
                    unsigned v = __hip_atomic_load(&arrive[((layer + 1) * 64 + lane) * 32],
                                  __ATOMIC_RELAXED, __HIP_MEMORY_SCOPE_AGENT);
                    if (__all((int)v >= thr)) break;
                    if (++guard > SPIN_CAP) break;
                    __builtin_amdgcn_s_sleep(1);
                }
            }
        }

        // ---- A fragment base ----
        const bool isX = (layer == 0 && wv < 4);
        const short* fH; const short* fL = nullptr; int itg0;
        if (layer == 0) {
            if (wv < 4) {
                size_t xb = (size_t)((t >> 6) & 1) * XCH2 + (size_t)(t & 63) * XFT;
                fH = Xh + xb; fL = Xl + xb; itg0 = kt0;
            } else {
                size_t hb = (size_t)(0 * 4 + (t & 3)) * SBH;       // own h[t-1]
                fH = Hh + hb; itg0 = kt0 - 17;
            }
        } else if (layer == 1) {
            size_t hb;
            if (wv < 4) { hb = (size_t)(0 * 4 + ((t + 1) & 3)) * SBH; itg0 = kt0; }      // h0[t]
            else        { hb = (size_t)(1 * 4 + (t & 3)) * SBH;       itg0 = kt0 - 16; } // h1[t-1]
            fH = Hh + hb;
        } else {
            size_t hb;
            if (wv < 4) { hb = (size_t)(1 * 4 + ((t + 1) & 3)) * SBH; itg0 = kt0; }      // h1[t]
            else        { hb = (size_t)(2 * 4 + (t & 3)) * SBH;       itg0 = kt0 - 16; } // h2[t-1]
            fH = Hh + hb;
        }

        f32x4 acc[2][4];
#pragma unroll
        for (int jj = 0; jj < 2; ++jj)
#pragma unroll
            for (int bt = 0; bt < 4; ++bt) acc[jj][bt] = (f32x4){0.f, 0.f, 0.f, 0.f};

#define DO_TILE_X(IT)                                                        \
        {                                                                    \
            s16x8 aH0, aH1, aH2, aH3, aL0, aL1, aL2, aL3;                    \
            const int fb = (itg0 + (IT)) * 4;                                \
            const short* pH0 = fH + (size_t)(fb + 0) * 512 + lane * 8;       \
            const short* pH1 = fH + (size_t)(fb + 1) * 512 + lane * 8;       \
            const short* pH2 = fH + (size_t)(fb + 2) * 512 + lane * 8;       \
            const short* pH3 = fH + (size_t)(fb + 3) * 512 + lane * 8;       \
            const short* pL0 = fL + (size_t)(fb + 0) * 512 + lane * 8;       \
            const short* pL1 = fL + (size_t)(fb + 1) * 512 + lane * 8;       \
            const short* pL2 = fL + (size_t)(fb + 2) * 512 + lane * 8;       \
            const short* pL3 = fL + (size_t)(fb + 3) * 512 + lane * 8;       \
            LOAD16X8(aH0, aH1, aH2, aH3, aL0, aL1, aL2, aL3,                 \
                     pH0, pH1, pH2, pH3, pL0, pL1, pL2, pL3);                \
            _Pragma("unroll")                                                \
            for (int jj = 0; jj < 2; ++jj) {                                 \
                acc[jj][0] = MFB(aH0, WHr[jj][IT], acc[jj][0]);              \
                acc[jj][0] = MFB(aL0, WHr[jj][IT], acc[jj][0]);              \
                acc[jj][0] = MFB(aH0, WLr[jj][IT], acc[jj][0]);              \
                acc[jj][1] = MFB(aH1, WHr[jj][IT], acc[jj][1]);              \
                acc[jj][1] = MFB(aL1, WHr[jj][IT], acc[jj][1]);              \
                acc[jj][1] = MFB(aH1, WLr[jj][IT], acc[jj][1]);              \
                acc[jj][2] = MFB(aH2, WHr[jj][IT], acc[jj][2]);              \
                acc[jj][2] = MFB(aL2, WHr[jj][IT], acc[jj][2]);              \
                acc[jj][2] = MFB(aH2, WLr[jj][IT], acc[jj][2]);              \
                acc[jj][3] = MFB(aH3, WHr[jj][IT], acc[jj][3]);              \
                acc[jj][3] = MFB(aL3, WHr[jj][IT], acc[jj][3]);              \
                acc[jj][3] = MFB(aH3, WLr[jj][IT], acc[jj][3]);              \
            }                                                                \
        }

#define DO_TILE_H(IT)                                                        \
        {                                                                    \
            s16x8 aH0, aH1, aH2, aH3;                                        \
            const int fb = (itg0 + (IT)) * 4;                                \
            const short* pH0 = fH + (size_t)(fb + 0) * 512 + lane * 8;       \
            const short* pH1 = fH + (size_t)(fb + 1) * 512 + lane * 8;       \
            const short* pH2 = fH + (size_t)(fb + 2) * 512 + lane * 8;       \
            const short* pH3 = fH + (size_t)(fb + 3) * 512 + lane * 8;       \
            LOAD16X4(aH0, aH1, aH2, aH3, pH0, pH1, pH2, pH3);                \
            _Pragma("unroll")                                                \
            for (int jj = 0; jj < 2; ++jj) {                                 \
                acc[jj][0] = MFB(aH0, WHr[jj][IT], acc[jj][0]);              \
                acc[jj][0] = MFB(aH0, WLr[jj][IT], acc[jj][0]);              \
                acc[jj][1] = MFB(aH1, WHr[jj][IT], acc[jj][1]);              \
                acc[jj][1] = MFB(aH1, WLr[jj][IT], acc[jj][1]);              \
                acc[jj][2] = MFB(aH2, WHr[jj][IT], acc[jj][2]);              \
                acc[jj][2] = MFB(aH2, WLr[jj][IT], acc[jj][2]);              \
                acc[jj][3] = MFB(aH3, WHr[jj][IT], acc[jj][3]);              \
                acc[jj][3] = MFB(aH3, WLr[jj][IT], acc[jj][3]);              \
            }                                                                \
        }

        if (isX) {
            DO_TILE_X(0)
            DO_TILE_X(1)
            DO_TILE_X(2)
            DO_TILE_X(3)
            if (wv == 0) DO_TILE_X(4)   // L0 wave 0 owns 5 k-tiles
        } else {
            DO_TILE_H(0)
            DO_TILE_H(1)
            DO_TILE_H(2)
            DO_TILE_H(3)
        }
#undef DO_TILE_X
#undef DO_TILE_H

        // ---- partial reduce across 8 waves ----
        __syncthreads();   // prev step's readers of PfF done
#pragma unroll
        for (int jj = 0; jj < 2; ++jj)
#pragma unroll
            for (int bt = 0; bt < 4; ++bt)
#pragma unroll
                for (int r = 0; r < 4; ++r)
                    PfF[(wv * 32 + jj * 16 + rl) * 65 + bt * 16 + g * 4 + r] = acc[jj][bt][r];
        __syncthreads();

        {   // gates + pointwise: 512 threads cover (ul 0..7) x (b 0..63)
            const int half = tid >> 8;             // 0..1
            const int r5 = tid & 255;
            const int ul = r5 >> 5, bl = r5 & 31;
            const int b = half * 32 + bl;
            float G[4];
#pragma unroll
            for (int gi = 0; gi < 4; ++gi) {
                const int jl = ul * 4 + gi;
                float v = 0.f;
#pragma unroll
                for (int w8 = 0; w8 < 8; ++w8)
                    v += PfF[(w8 * 32 + jl) * 65 + b];
                G[gi] = v + biasLDS[jl];
            }
            float cold = cLDS[ul * 64 + b];
            float cn = sigf(G[1]) * cold + sigf(G[0]) * tanhf(G[2]);
            float hn = sigf(G[3]) * tanhf(cn);
            cLDS[ul * 64 + b] = cn;
            hstH[b * 8 + ul] = f2bf(hn);
        }
        __syncthreads();

        if (tid < 64) {
            // write h slice -> single-bf16 blob slot (t+1)&3 (write-through)
            // (WAR for this slot was prepolled at top of step)
            const int b = tid, bt = b >> 4, prl = b & 15;
            const size_t base = (size_t)(layer * 4 + ((t + 1) & 3)) * SBH
                              + (size_t)(p_it * 4 + bt) * 512 + p_hf * 4;
            const size_t aA = base + (size_t)(p_gA * 16 + prl) * 8;
            const size_t aB = base + (size_t)((p_gA + 1) * 16 + prl) * 8;
            s16x8 vh = *(const s16x8*)(hstH + b * 8);
            astore8(Hh + aA, lo4(vh));
            astore8(Hh + aB, hi4(vh));
        }

        // ---- x-transpose of NEXT chunk at end of steps t%64==63 (layer 0) ----
        if (layer == 0 && (t & 63) == 63 && t < 448) {
            const int c = (t >> 6) + 1;            // chunks 1..7
            const int slot = c & 1;
            const int b = jb;                       // own batch row
            __syncthreads();                        // gates done; safe to alias PfF
            float* tileF = PfF;                     // [64][65]
#pragma unroll 1
            for (int i = 0; i < 9; ++i) {
                const int f0 = i * 64;
#pragma unroll
                for (int rr = 0; rr < 8; ++rr) {
                    const int fl = (tid >> 6) + rr * 8;
                    const int tt2 = tid & 63;
                    const int f = f0 + fl;
                    tileF[fl * 65 + tt2] = (f < FF) ? x[((size_t)b * FF + f) * TT + (size_t)c * 64 + tt2] : 0.f;
                }
                __syncthreads();
                if (tid < 256) {
                    const int q = tid & 3, tt2 = tid >> 2;
                    const int fq = f0 + q * 16;
                    if (fq < KX) {
                        const int it2 = fq >> 5, hf = (fq >> 4) & 1;
                        s16x8 vh0, vl0, vh1, vl1;
#pragma unroll
                        for (int m = 0; m < 8; ++m) {
                            short hi, lo; bfsplit(tileF[(q * 16 + m) * 65 + tt2], hi, lo);
                            vh0[m] = hi; vl0[m] = lo;
                        }
#pragma unroll
                        for (int m = 0; m < 8; ++m) {
                            short hi, lo; bfsplit(tileF[(q * 16 + 8 + m) * 65 + tt2], hi, lo);
                            vh1[m] = hi; vl1[m] = lo;
                        }
                        size_t tb = (size_t)slot * XCH2 + (size_t)tt2 * XFT
                                  + (size_t)(it2 * 4 + (b >> 4)) * 512
                                  + (size_t)(b & 15) * 8 + hf * 4;
                        astore8(Xh + tb,       lo4(vh0));
                        astore8(Xh + tb + 128, hi4(vh0));
                        astore8(Xh + tb + 256, lo4(vh1));
                        astore8(Xh + tb + 384, hi4(vh1));
                        astore8(Xl + tb,       lo4(vl0));
                        astore8(Xl + tb + 128, hi4(vl0));
                        astore8(Xl + tb + 256, lo4(vl1));
                        astore8(Xl + tb + 384, hi4(vl1));
                    }
                }
                __syncthreads();
            }
            asm volatile("s_waitcnt vmcnt(0)" ::: "memory");   // drain x stores
            __syncthreads();   // all waves drained before tid0 flags
        }

        // ---- flag completion of step t ----
        if (tid == 0) {
            asm volatile("s_waitcnt vmcnt(0)" ::: "memory");   // drain wave0 h stores
            __hip_atomic_store(&arrive[bid * 32], (unsigned)(t + 1),
                               __ATOMIC_RELAXED, __HIP_MEMORY_SCOPE_AGENT);
        }
    }
}

// ---------- final FCs (fc1 reads single-bf16 fragment h3) ----------
__global__ __launch_bounds__(256) void fc1_k(
    const short* __restrict__ H3h,
    const float* __restrict__ W, const float* __restrict__ bias,
    float* __restrict__ hid)
{
    const int lane = (int)threadIdx.x & 63;                  // = b
    const int wv = __builtin_amdgcn_readfirstlane((int)threadIdx.x >> 6);
    const int n = (int)blockIdx.x * 4 + wv;                  // 0..511
    const int bt = lane >> 4, rl = lane & 15;
    float acc = 0.f;
    const float* wr = W + (size_t)n * HH;
    for (int it = 0; it < 16; ++it) {
#pragma unroll
        for (int hf = 0; hf < 2; ++hf) {
#pragma unroll
            for (int g4 = 0; g4 < 4; ++g4) {
                const int k = it * 32 + hf * 16 + g4 * 4;
                const int fa = ((it * 4 + bt) * 64 + g4 * 16 + rl) * 8 + hf * 4;
                s16x4 vh = *(const s16x4*)(H3h + fa);
#pragma unroll
                for (int i = 0; i < 4; ++i)
                    acc = fmaf(bf2f(vh[i]), wr[k + i], acc);
            }
        }
    }
    acc += bias[n];
    hid[(size_t)lane * HH + n] = fmaxf(acc, 0.f);
}

__global__ __launch_bounds__(256) void fc2_k(
    const float* __restrict__ hid, const float* __restrict__ W,
    const float* __restrict__ bias, float* __restrict__ out)
{
    const int lane = (int)threadIdx.x & 63;                  // = b
    const int wv = __builtin_amdgcn_readfirstlane((int)threadIdx.x >> 6);
    const int n = (int)blockIdx.x * 4 + wv;                  // 0..515
    if (n >= FF) return;
    float acc = 0.f;
    const float* wr = W + (size_t)n * HH;
    const float* hp = hid + (size_t)lane * HH;
    for (int k = 0; k < HH; k += 8) {
        float4 a = *(const float4*)(hp + k);
        float4 b = *(const float4*)(hp + k + 4);
        acc = fmaf(a.x, wr[k+0], acc); acc = fmaf(a.y, wr[k+1], acc);
        acc = fmaf(a.z, wr[k+2], acc); acc = fmaf(a.w, wr[k+3], acc);
        acc = fmaf(b.x, wr[k+4], acc); acc = fmaf(b.y, wr[k+5], acc);
        acc = fmaf(b.z, wr[k+6], acc); acc = fmaf(b.w, wr[k+7], acc);
    }
    out[(size_t)lane * FF + n] = acc + bias[n];
}

extern "C" void kernel_launch(void* const* d_in, const int* in_sizes, int n_in,
                              void* d_out, int out_size, void* d_ws, size_t ws_size,
                              hipStream_t stream)
{
    const float* x     = (const float*)d_in[0];
    const float* Wih1  = (const float*)d_in[1];
    const float* Whh1  = (const float*)d_in[2];
    const float* bih1  = (const float*)d_in[3];
    const float* bhh1  = (const float*)d_in[4];
    const float* Wih2  = (const float*)d_in[5];
    const float* Whh2  = (const float*)d_in[6];
    const float* bih2  = (const float*)d_in[7];
    const float* bhh2  = (const float*)d_in[8];
    const float* Wih3  = (const float*)d_in[9];
    const float* Whh3  = (const float*)d_in[10];
    const float* bih3  = (const float*)d_in[11];
    const float* bhh3  = (const float*)d_in[12];
    const float* fc1_w = (const float*)d_in[13];
    const float* fc1_b = (const float*)d_in[14];
    const float* fc2_w = (const float*)d_in[15];
    const float* fc2_b = (const float*)d_in[16];

    char* p = (char*)d_ws;
    unsigned* arrive = (unsigned*)p;                       // GRID*32 u32 slots
    p = (char*)d_ws + 32768;            // barrier region (memset each call)
    float* cT   = (float*)p;            p += (size_t)3 * HH * BB * 4;
    float* hid  = (float*)p;            p += (size_t)HH * BB * 4;
    float* bsum = (float*)p;            p += 6144 * 4;
    short* Hh   = (short*)p;            p += (size_t)12 * SBH * 2;   // 3 layers x 4 slots
    short* Xh   = (short*)p;            p += (size_t)2 * XCH2 * 2;
    short* Xl   = (short*)p;            p += (size_t)2 * XCH2 * 2;
    short* Bh   = (short*)p;            p += (size_t)TOTB * 2;
    short* Bl   = (short*)p;            p += (size_t)TOTB * 2;
    if ((size_t)(p - (char*)d_ws) > ws_size) return;

    hipMemsetAsync(d_ws, 0, 32768, stream);
    prep_state_h<<<384, 256, 0, stream>>>(
        (const float*)d_in[17], (const float*)d_in[19], (const float*)d_in[21], Hh);
    prep_state_c<<<24, 256, 0, stream>>>(
        (const float*)d_in[18], (const float*)d_in[20], (const float*)d_in[22], cT);
    prep_bias<<<24, 256, 0, stream>>>(bih1, bhh1, bih2, bhh2, bih3, bhh3, bsum);
    prep_blob<<<TOTB / 256, 256, 0, stream>>>(Wih1, Whh1, Wih2, Whh2, Wih3, Whh3, Bh, Bl);
    prep_x<<<576, 256, 0, stream>>>(x, Xh, Xl);

    lstm_persist<<<GRID, 512, 0, stream>>>(x, Bh, Bl, Xh, Xl, Hh, bsum, cT, arrive);

    // final h3 = h_2[511] -> slot (511+1)&3 = 0 -> layer2 slot0 = +8*SBH
    fc1_k<<<128, 256, 0, stream>>>(Hh + (size_t)8 * SBH, fc1_w, fc1_b, hid);
    fc2_k<<<129, 256, 0, stream>>>(hid, fc2_w, fc2_b, (float*)d_out);
}